// Round 1
// baseline (178.517 us; speedup 1.0000x reference)
//
#include <hip/hip_runtime.h>

// MultiEmbed: joint = emb_t[t] + emb_l[l] + emb_u[u]  (B,N,E)   = 1 MB
//             delta = base[m] + (ds/100)*d1[m] + (dt/1000)*d2[m] (B,N,N,E) = 134 MB
// Write-stream memory-bound. v2: the per-iteration dependency chain
// (s_load traj_len -> ballot -> branch -> dd load -> fma -> store) is hoisted
// entirely out of the loop. Prologue precomputes two 16-bit wave-uniform
// classification masks (all-valid / all-invalid per iteration) and all 16
// traj_len values; the loop is fully unrolled so all 16 mat loads issue
// up-front. Inner body: scalar bit-test + 10 VALU + 1 nt store.

#define HOURS 168
#define BB 32
#define NN 128
#define EE 64
#define JOINT_ELEMS (BB * NN * EE)            // 262144 floats
#define JOINT4      (JOINT_ELEMS / 4)         // 65536 float4 items
#define DELTA4      (BB * NN * NN * EE / 4)   // 8388608 float4 items
#define NBLOCKS     2048
#define NTHREADS    (NBLOCKS * 256)           // 524288 = grid stride
#define ITERS       (DELTA4 / NTHREADS)       // exactly 16, no remainder

typedef float f32x4 __attribute__((ext_vector_type(4)));

__device__ __forceinline__ f32x4 ld4(const float* p) {
    return *(const f32x4*)p;
}

__global__ __launch_bounds__(256) void multiembed_kernel(
    const int*   __restrict__ traj,     // (B,N,3)
    const float* __restrict__ mat,      // (B,N,N,2)
    const int*   __restrict__ traj_len, // (B,)
    const float* __restrict__ emb_t,    // (169,E)
    const float* __restrict__ emb_l,    // (100000,E)
    const float* __restrict__ emb_u,    // (10000,E)
    const float* __restrict__ emb_su,   // (2,E)
    const float* __restrict__ emb_sl,   // (2,E)
    const float* __restrict__ emb_tu,   // (2,E)
    const float* __restrict__ emb_tl,   // (2,E)
    float*       __restrict__ out)      // joint | delta, flat
{
    const int tid = blockIdx.x * blockDim.x + threadIdx.x;
    const int e   = (tid & 15) * 4;     // this thread's fixed E-slot

    // ---- preload the 2xE tables at this E-slot, folded into lerp form ----
    const f32x4 sl0 = ld4(emb_sl + e), sl1 = ld4(emb_sl + EE + e);
    const f32x4 su0 = ld4(emb_su + e), su1 = ld4(emb_su + EE + e);
    const f32x4 tl0 = ld4(emb_tl + e), tl1 = ld4(emb_tl + EE + e);
    const f32x4 tu0 = ld4(emb_tu + e), tu1 = ld4(emb_tu + EE + e);

    const f32x4 base0 = sl0 + tl0, base1 = sl1 + tl1;
    const f32x4 d1_0  = su0 - sl0, d1_1  = su1 - sl1;
    const f32x4 d2_0  = tu0 - tl0, d2_1  = tu1 - tl1;

    // ---- joint: first 65536 threads produce one float4 each ----
    if (tid < JOINT4) {
        const int cell = tid >> 4;              // b*N + n
        const int u = traj[cell * 3 + 0];
        const int l = traj[cell * 3 + 1];
        const int t = traj[cell * 3 + 2];
        int tm = (t - 1) % HOURS;               // python-style mod
        if (tm < 0) tm += HOURS;
        tm += 1;                                // 1..168
        f32x4 v = ld4(emb_t + tm * EE + e) + ld4(emb_l + (size_t)l * EE + e)
                + ld4(emb_u + (size_t)u * EE + e);
        __builtin_nontemporal_store(v, (f32x4*)(out + (size_t)tid * 4));
    }

    // ---- delta: exactly 16 iterations per thread, stride NTHREADS ----
    const int cell0 = tid >> 4;                       // 0..32767
    // invariants: stride/16 = 32768 cells/iter; 32768 % 128 == 0 and
    // (32768>>7) % 128 == 0  =>  j and i are loop-invariant; b += 2 per iter.
    const int j  = cell0 & (NN - 1);
    const int i  = (cell0 >> 7) & (NN - 1);
    const int mx = (i > j) ? i : j;                   // m == (mx < L)
    // b0 is wave-uniform (64 consecutive tids span 4 consecutive cells,
    // and cell/16384 is constant across them) -> force scalar.
    const int b0 = __builtin_amdgcn_readfirstlane(cell0 >> 14);   // 0 or 1

    // ---- prologue: hoist ALL per-iteration scalar work out of the loop ----
    // traj_len values for b = b0, b0+2, ..., b0+30 (all scalar loads, one wait)
    int Ls[ITERS];
    #pragma unroll
    for (int k = 0; k < ITERS; ++k)
        Ls[k] = traj_len[b0 + 2 * k];

    // wave-uniform classification masks: bit k set -> iteration k is
    // all-valid / all-invalid for this wave. __ballot is uniform -> SGPR.
    unsigned allv = 0, allz = 0;
    #pragma unroll
    for (int k = 0; k < ITERS; ++k) {
        const unsigned long long bal = __ballot(mx < Ls[k]);
        allv |= (unsigned)(bal == 0xFFFFFFFFFFFFFFFFull) << k;
        allz |= (unsigned)(bal == 0ull) << k;
    }

    const float* mptr = mat + (size_t)cell0 * 2;      // +65536 floats/iter
    float*       dptr = out + JOINT_ELEMS + (size_t)tid * 4;  // +NTHREADS*4/iter

    // ---- main loop: fully unrolled, zero loop-carried dependencies.
    // All 16 float2 mat loads can issue before the first store needs one.
    #pragma unroll
    for (int k = 0; k < ITERS; ++k) {
        const float2 dd  = *(const float2*)(mptr + (size_t)k * (32768 * 2));
        const float  csu = dd.x * 0.01f;              // ds/(SU-SL)
        const float  ctu = dd.y * 0.001f;             // dt/(TU-TL)

        f32x4 bse, v1, v2;
        if (allv & (1u << k)) {                       // all-valid (common)
            bse = base1; v1 = d1_1; v2 = d2_1;
        } else if (allz & (1u << k)) {                // all-invalid (common)
            bse = base0; v1 = d1_0; v2 = d2_0;
        } else {                                      // boundary wave (rare)
            const bool m = mx < Ls[k];
            bse = m ? base1 : base0;
            v1  = m ? d1_1  : d1_0;
            v2  = m ? d2_1  : d2_0;
        }

        const f32x4 r = bse + csu * v1 + ctu * v2;    // fp-contract -> fma
        __builtin_nontemporal_store(r, (f32x4*)(dptr + (size_t)k * (NTHREADS * 4)));
    }
}

extern "C" void kernel_launch(void* const* d_in, const int* in_sizes, int n_in,
                              void* d_out, int out_size, void* d_ws, size_t ws_size,
                              hipStream_t stream) {
    const int*   traj     = (const int*)  d_in[0];
    const float* mat      = (const float*)d_in[1];
    const int*   traj_len = (const int*)  d_in[2];
    const float* emb_t    = (const float*)d_in[3];
    const float* emb_l    = (const float*)d_in[4];
    const float* emb_u    = (const float*)d_in[5];
    const float* emb_su   = (const float*)d_in[6];
    const float* emb_sl   = (const float*)d_in[7];
    const float* emb_tu   = (const float*)d_in[8];
    const float* emb_tl   = (const float*)d_in[9];
    float*       out      = (float*)d_out;

    multiembed_kernel<<<dim3(NBLOCKS), dim3(256), 0, stream>>>(
        traj, mat, traj_len, emb_t, emb_l, emb_u,
        emb_su, emb_sl, emb_tu, emb_tl, out);
}

// Round 2
// 173.143 us; speedup vs baseline: 1.0310x; 1.0310x over previous
//
#include <hip/hip_runtime.h>

// MultiEmbed: joint = emb_t[t] + emb_l[l] + emb_u[u]  (B,N,E)   = 1 MB
//             delta = base[m] + (ds/100)*d1[m] + (dt/1000)*d2[m] (B,N,N,E) = 134 MB
// Write-stream memory-bound. v3: single change vs v2 — drop
// __builtin_nontemporal_store, use plain stores. Theory: gfx950's `nt`
// cache policy throttles the store stream (~1.9 TB/s observed) while the
// plain write-through path (what fillBufferAligned uses) runs at 6.5 TB/s.
// Everything else (hoisted scalar masks, full unroll) identical to v2.

#define HOURS 168
#define BB 32
#define NN 128
#define EE 64
#define JOINT_ELEMS (BB * NN * EE)            // 262144 floats
#define JOINT4      (JOINT_ELEMS / 4)         // 65536 float4 items
#define DELTA4      (BB * NN * NN * EE / 4)   // 8388608 float4 items
#define NBLOCKS     2048
#define NTHREADS    (NBLOCKS * 256)           // 524288 = grid stride
#define ITERS       (DELTA4 / NTHREADS)       // exactly 16, no remainder

typedef float f32x4 __attribute__((ext_vector_type(4)));

__device__ __forceinline__ f32x4 ld4(const float* p) {
    return *(const f32x4*)p;
}

__global__ __launch_bounds__(256) void multiembed_kernel(
    const int*   __restrict__ traj,     // (B,N,3)
    const float* __restrict__ mat,      // (B,N,N,2)
    const int*   __restrict__ traj_len, // (B,)
    const float* __restrict__ emb_t,    // (169,E)
    const float* __restrict__ emb_l,    // (100000,E)
    const float* __restrict__ emb_u,    // (10000,E)
    const float* __restrict__ emb_su,   // (2,E)
    const float* __restrict__ emb_sl,   // (2,E)
    const float* __restrict__ emb_tu,   // (2,E)
    const float* __restrict__ emb_tl,   // (2,E)
    float*       __restrict__ out)      // joint | delta, flat
{
    const int tid = blockIdx.x * blockDim.x + threadIdx.x;
    const int e   = (tid & 15) * 4;     // this thread's fixed E-slot

    // ---- preload the 2xE tables at this E-slot, folded into lerp form ----
    const f32x4 sl0 = ld4(emb_sl + e), sl1 = ld4(emb_sl + EE + e);
    const f32x4 su0 = ld4(emb_su + e), su1 = ld4(emb_su + EE + e);
    const f32x4 tl0 = ld4(emb_tl + e), tl1 = ld4(emb_tl + EE + e);
    const f32x4 tu0 = ld4(emb_tu + e), tu1 = ld4(emb_tu + EE + e);

    const f32x4 base0 = sl0 + tl0, base1 = sl1 + tl1;
    const f32x4 d1_0  = su0 - sl0, d1_1  = su1 - sl1;
    const f32x4 d2_0  = tu0 - tl0, d2_1  = tu1 - tl1;

    // ---- joint: first 65536 threads produce one float4 each ----
    if (tid < JOINT4) {
        const int cell = tid >> 4;              // b*N + n
        const int u = traj[cell * 3 + 0];
        const int l = traj[cell * 3 + 1];
        const int t = traj[cell * 3 + 2];
        int tm = (t - 1) % HOURS;               // python-style mod
        if (tm < 0) tm += HOURS;
        tm += 1;                                // 1..168
        f32x4 v = ld4(emb_t + tm * EE + e) + ld4(emb_l + (size_t)l * EE + e)
                + ld4(emb_u + (size_t)u * EE + e);
        *(f32x4*)(out + (size_t)tid * 4) = v;   // plain store (v3)
    }

    // ---- delta: exactly 16 iterations per thread, stride NTHREADS ----
    const int cell0 = tid >> 4;                       // 0..32767
    // invariants: stride/16 = 32768 cells/iter; 32768 % 128 == 0 and
    // (32768>>7) % 128 == 0  =>  j and i are loop-invariant; b += 2 per iter.
    const int j  = cell0 & (NN - 1);
    const int i  = (cell0 >> 7) & (NN - 1);
    const int mx = (i > j) ? i : j;                   // m == (mx < L)
    // b0 is wave-uniform (64 consecutive tids span 4 consecutive cells,
    // and cell/16384 is constant across them) -> force scalar.
    const int b0 = __builtin_amdgcn_readfirstlane(cell0 >> 14);   // 0 or 1

    // ---- prologue: hoist ALL per-iteration scalar work out of the loop ----
    int Ls[ITERS];
    #pragma unroll
    for (int k = 0; k < ITERS; ++k)
        Ls[k] = traj_len[b0 + 2 * k];

    // wave-uniform classification masks: bit k set -> iteration k is
    // all-valid / all-invalid for this wave. __ballot is uniform -> SGPR.
    unsigned allv = 0, allz = 0;
    #pragma unroll
    for (int k = 0; k < ITERS; ++k) {
        const unsigned long long bal = __ballot(mx < Ls[k]);
        allv |= (unsigned)(bal == 0xFFFFFFFFFFFFFFFFull) << k;
        allz |= (unsigned)(bal == 0ull) << k;
    }

    const float* mptr = mat + (size_t)cell0 * 2;      // +65536 floats/iter
    float*       dptr = out + JOINT_ELEMS + (size_t)tid * 4;  // +NTHREADS*4/iter

    // ---- main loop: fully unrolled, zero loop-carried dependencies ----
    #pragma unroll
    for (int k = 0; k < ITERS; ++k) {
        const float2 dd  = *(const float2*)(mptr + (size_t)k * (32768 * 2));
        const float  csu = dd.x * 0.01f;              // ds/(SU-SL)
        const float  ctu = dd.y * 0.001f;             // dt/(TU-TL)

        f32x4 bse, v1, v2;
        if (allv & (1u << k)) {                       // all-valid (common)
            bse = base1; v1 = d1_1; v2 = d2_1;
        } else if (allz & (1u << k)) {                // all-invalid (common)
            bse = base0; v1 = d1_0; v2 = d2_0;
        } else {                                      // boundary wave (rare)
            const bool m = mx < Ls[k];
            bse = m ? base1 : base0;
            v1  = m ? d1_1  : d1_0;
            v2  = m ? d2_1  : d2_0;
        }

        const f32x4 r = bse + csu * v1 + ctu * v2;    // fp-contract -> fma
        *(f32x4*)(dptr + (size_t)k * (NTHREADS * 4)) = r;   // plain store (v3)
    }
}

extern "C" void kernel_launch(void* const* d_in, const int* in_sizes, int n_in,
                              void* d_out, int out_size, void* d_ws, size_t ws_size,
                              hipStream_t stream) {
    const int*   traj     = (const int*)  d_in[0];
    const float* mat      = (const float*)d_in[1];
    const int*   traj_len = (const int*)  d_in[2];
    const float* emb_t    = (const float*)d_in[3];
    const float* emb_l    = (const float*)d_in[4];
    const float* emb_u    = (const float*)d_in[5];
    const float* emb_su   = (const float*)d_in[6];
    const float* emb_sl   = (const float*)d_in[7];
    const float* emb_tu   = (const float*)d_in[8];
    const float* emb_tl   = (const float*)d_in[9];
    float*       out      = (float*)d_out;

    multiembed_kernel<<<dim3(NBLOCKS), dim3(256), 0, stream>>>(
        traj, mat, traj_len, emb_t, emb_l, emb_u,
        emb_su, emb_sl, emb_tu, emb_tl, out);
}